// Round 1
// 6416.141 us; speedup vs baseline: 1.5574x; 1.5574x over previous
//
#include <hip/hip_runtime.h>
#include <math.h>

#define B_ 8
#define S_ 2048
#define E_ 1024
#define H_ 1024
#define M_ 16384   // B_*S_

typedef __attribute__((ext_vector_type(8))) short short8;    // 8 bf16 = 4 VGPRs
typedef __attribute__((ext_vector_type(4))) float floatx4;

// ---------------- block-wide reduction of two floats (256 threads = 4 waves) ----------------
__device__ __forceinline__ void block_reduce2(float &a, float &b) {
#pragma unroll
  for (int off = 32; off > 0; off >>= 1) {
    a += __shfl_down(a, off);
    b += __shfl_down(b, off);
  }
  __shared__ float sa[4], sb[4];
  const int w = threadIdx.x >> 6;
  __syncthreads();                 // protects reuse across back-to-back calls
  if ((threadIdx.x & 63) == 0) { sa[w] = a; sb[w] = b; }
  __syncthreads();
  a = sa[0] + sa[1] + sa[2] + sa[3];
  b = sb[0] + sb[1] + sb[2] + sb[3];
}

// ---------------- LayerNorm(x) -> x_norm, plus delta = softplus(x_norm . delta_w + delta_b) ----------------
__global__ __launch_bounds__(256) void ln_delta_kernel(
    const float* __restrict__ x, const float* __restrict__ g, const float* __restrict__ bt,
    const float* __restrict__ dw, const float* __restrict__ db,
    float* __restrict__ xn, float* __restrict__ delta)
{
  const int row = blockIdx.x;
  const int t = threadIdx.x;
  const float4 v = ((const float4*)(x + (size_t)row * E_))[t];
  float s1 = v.x + v.y + v.z + v.w;
  float s2 = v.x*v.x + v.y*v.y + v.z*v.z + v.w*v.w;
  block_reduce2(s1, s2);
  const float mean = s1 * (1.f / E_);
  const float var  = s2 * (1.f / E_) - mean * mean;
  const float rstd = rsqrtf(var + 1e-5f);
  const float4 g4 = ((const float4*)g)[t];
  const float4 b4 = ((const float4*)bt)[t];
  float4 o;
  o.x = (v.x - mean) * rstd * g4.x + b4.x;
  o.y = (v.y - mean) * rstd * g4.y + b4.y;
  o.z = (v.z - mean) * rstd * g4.z + b4.z;
  o.w = (v.w - mean) * rstd * g4.w + b4.w;
  ((float4*)(xn + (size_t)row * E_))[t] = o;
  const float4 d4 = ((const float4*)dw)[t];
  float dd = o.x*d4.x + o.y*d4.y + o.z*d4.z + o.w*d4.w;
  float dummy = 0.f;
  block_reduce2(dd, dummy);
  if (t == 0) {
    const float z = dd + db[0];
    delta[row] = (z > 20.f) ? z : log1pf(__expf(z));
  }
}

// ---------------- per-row mean/rstd of reservoir states (for fused ro-layernorm) ----------------
__global__ __launch_bounds__(256) void rowstats_kernel(
    const float* __restrict__ res, float2* __restrict__ st)
{
  const int row = blockIdx.x;
  const int t = threadIdx.x;
  const float4 v = ((const float4*)(res + (size_t)row * H_))[t];
  float s1 = v.x + v.y + v.z + v.w;
  float s2 = v.x*v.x + v.y*v.y + v.z*v.z + v.w*v.w;
  block_reduce2(s1, s2);
  if (t == 0) {
    const float m = s1 * (1.f / H_);
    const float var = s2 * (1.f / H_) - m * m;
    st[row] = make_float2(m, rsqrtf(var + 1e-5f));
  }
}

// ---------------- bf16 MFMA GEMM: C[M,N] = act(A[M,1024] @ W[N,1024]^T + bias) ----------------
__device__ __forceinline__ unsigned pack_bf16(float lo, float hi) {
  return __builtin_amdgcn_perm(__float_as_uint(hi) + 0x8000u,
                               __float_as_uint(lo) + 0x8000u, 0x07060302u);
}

template<int ACT>
__global__ __launch_bounds__(256) void gemm_bf16_nt(
    const float* __restrict__ A, const float* __restrict__ W,
    const float* __restrict__ bias, float* __restrict__ C)
{
  __shared__ __align__(16) unsigned short As[128 * 40];
  __shared__ __align__(16) unsigned short Ws[128 * 40];
  const int tid  = threadIdx.x;
  const int bn   = blockIdx.x & 7;
  const int bm   = blockIdx.x >> 3;
  const int wave = tid >> 6, lane = tid & 63;
  const int wm = (wave >> 1) * 64, wn = (wave & 1) * 64;
  const int fm = lane & 15, quad = lane >> 4;

  floatx4 acc[4][4];
#pragma unroll
  for (int i = 0; i < 4; ++i)
#pragma unroll
    for (int j = 0; j < 4; ++j) acc[i][j] = (floatx4){0.f, 0.f, 0.f, 0.f};

  const float* Abase = A + (size_t)bm * 128 * 1024;
  const float* Wbase = W + (size_t)bn * 128 * 1024;

  for (int k0 = 0; k0 < 1024; k0 += 32) {
    float4 a4[4], w4[4];
#pragma unroll
    for (int i = 0; i < 4; ++i) {
      const int q = tid + 256 * i;
      const int row = q >> 3, ch = q & 7;
      a4[i] = *(const float4*)(Abase + (size_t)row * 1024 + k0 + ch * 4);
      w4[i] = *(const float4*)(Wbase + (size_t)row * 1024 + k0 + ch * 4);
    }
#pragma unroll
    for (int i = 0; i < 4; ++i) {
      const int q = tid + 256 * i;
      const int row = q >> 3, ch = q & 7;
      uint2 pa, pw;
      pa.x = pack_bf16(a4[i].x, a4[i].y); pa.y = pack_bf16(a4[i].z, a4[i].w);
      pw.x = pack_bf16(w4[i].x, w4[i].y); pw.y = pack_bf16(w4[i].z, w4[i].w);
      *(uint2*)(&As[row * 40 + ch * 4]) = pa;
      *(uint2*)(&Ws[row * 40 + ch * 4]) = pw;
    }
    __syncthreads();
    short8 af[4], wf[4];
#pragma unroll
    for (int i = 0; i < 4; ++i) {
      af[i] = *(const short8*)(&As[(wm + i * 16 + fm) * 40 + quad * 8]);
      wf[i] = *(const short8*)(&Ws[(wn + i * 16 + fm) * 40 + quad * 8]);
    }
#pragma unroll
    for (int i = 0; i < 4; ++i)
#pragma unroll
      for (int j = 0; j < 4; ++j)
        acc[i][j] = __builtin_amdgcn_mfma_f32_16x16x32_bf16(af[i], wf[j], acc[i][j], 0, 0, 0);
    __syncthreads();
  }

  // epilogue: C/D layout col=lane&15, row=quad*4+reg (m89/m91)
#pragma unroll
  for (int i = 0; i < 4; ++i) {
    const int grow0 = bm * 128 + wm + i * 16 + quad * 4;
#pragma unroll
    for (int j = 0; j < 4; ++j) {
      const int gcol = bn * 128 + wn + j * 16 + fm;
      const float bb = (ACT == 1) ? bias[gcol] : 0.f;
#pragma unroll
      for (int r = 0; r < 4; ++r) {
        float v = acc[i][j][r] + bb;
        if (ACT == 1) v = 1.f / (1.f + __expf(-v));
        C[(size_t)(grow0 + r) * 1024 + gcol] = v;
      }
    }
  }
}

// ---------------- readout GEMM: fused ro-layernorm on A, gelu, ssm reconstruction, gate blend ----------------
__global__ __launch_bounds__(256) void gemm_readout_kernel(
    const float* __restrict__ A,      // reservoir states [M,1024]
    const float* __restrict__ W,      // ro_w [1024,1024]
    const float* __restrict__ bias,   // ro_bias
    const float2* __restrict__ lnst,  // per-row mean/rstd
    const float* __restrict__ lng, const float* __restrict__ lnb,
    const float* __restrict__ Avec,   // A[h]
    const float* __restrict__ cumd,   // within-chunk cumulative delta [M]
    const float* __restrict__ chH,    // per-chunk initial ssm state [B,16,1024]
    const float* __restrict__ gate,   // [M,1024]
    float* __restrict__ C)            // d_out: in = ssm local states, out = final
{
  __shared__ float As[16][132];
  __shared__ float Wt[16][68];
  const int tid = threadIdx.x;
  const int bn = blockIdx.x & 15;
  const int bm = blockIdx.x >> 4;
  const int tx = tid & 15;
  const int ty = tid >> 4;
  const int sr = tid >> 2;
  const int sk = tid & 3;
  float acc[8][4];
#pragma unroll
  for (int i = 0; i < 8; ++i)
#pragma unroll
    for (int j = 0; j < 4; ++j) acc[i][j] = 0.f;

  for (int k0 = 0; k0 < 1024; k0 += 16) {
    const float4 g4 = *(const float4*)(lng + k0 + sk * 4);
    const float4 b4 = *(const float4*)(lnb + k0 + sk * 4);
#pragma unroll
    for (int p = 0; p < 2; ++p) {
      const int row = sr + p * 64;
      const int gr = bm * 128 + row;
      float4 a4 = *(const float4*)(A + (size_t)gr * 1024 + k0 + sk * 4);
      const float2 st = lnst[gr];
      a4.x = (a4.x - st.x) * st.y * g4.x + b4.x;
      a4.y = (a4.y - st.x) * st.y * g4.y + b4.y;
      a4.z = (a4.z - st.x) * st.y * g4.z + b4.z;
      a4.w = (a4.w - st.x) * st.y * g4.w + b4.w;
      As[sk*4+0][row] = a4.x; As[sk*4+1][row] = a4.y;
      As[sk*4+2][row] = a4.z; As[sk*4+3][row] = a4.w;
    }
    {
      const float4 w4 = *(const float4*)(W + (size_t)(bn * 64 + sr) * 1024 + k0 + sk * 4);
      Wt[sk*4+0][sr] = w4.x; Wt[sk*4+1][sr] = w4.y;
      Wt[sk*4+2][sr] = w4.z; Wt[sk*4+3][sr] = w4.w;
    }
    __syncthreads();
#pragma unroll
    for (int kk = 0; kk < 16; ++kk) {
      const float4 a0 = *(const float4*)&As[kk][ty * 4];
      const float4 a1 = *(const float4*)&As[kk][64 + ty * 4];
      const float4 b0 = *(const float4*)&Wt[kk][tx * 4];
      const float ar[8] = {a0.x,a0.y,a0.z,a0.w,a1.x,a1.y,a1.z,a1.w};
      const float bc[4] = {b0.x,b0.y,b0.z,b0.w};
#pragma unroll
      for (int i = 0; i < 8; ++i)
#pragma unroll
        for (int j = 0; j < 4; ++j)
          acc[i][j] += ar[i] * bc[j];
    }
    __syncthreads();
  }
  const int col0 = bn * 64 + tx * 4;
  const float4 Ah4 = *(const float4*)(Avec + col0);
  const float4 bs4 = *(const float4*)(bias + col0);
  const float Ah[4] = {Ah4.x, Ah4.y, Ah4.z, Ah4.w};
  const float bv[4] = {bs4.x, bs4.y, bs4.z, bs4.w};
#pragma unroll
  for (int i = 0; i < 8; ++i) {
    const int gr = bm * 128 + ((i < 4) ? (ty * 4 + i) : (64 + ty * 4 + i - 4));
    const int b = gr >> 11;          // gr = b*2048 + s
    const int s = gr & 2047;
    const int c = s >> 7;            // 128-step chunk
    const float cd = cumd[gr];
    const size_t off = (size_t)gr * 1024 + col0;
    const float4 hin4 = *(const float4*)(chH + (size_t)((b * 16 + c) << 10) + col0);
    const float4 lcl4 = *(const float4*)(C + off);
    const float4 gt4  = *(const float4*)(gate + off);
    const float hin[4] = {hin4.x, hin4.y, hin4.z, hin4.w};
    const float lcl[4] = {lcl4.x, lcl4.y, lcl4.z, lcl4.w};
    const float gt[4]  = {gt4.x, gt4.y, gt4.z, gt4.w};
    float4 o;
    float* po = &o.x;
#pragma unroll
    for (int j = 0; j < 4; ++j) {
      float v = acc[i][j] + bv[j];
      v = 0.5f * v * (1.f + erff(v * 0.70710678118654752f));   // exact gelu
      const float p = __expf(Ah[j] * cd);                      // prod of A_bar over chunk prefix
      const float sst = lcl[j] + p * hin[j];                   // true ssm state
      po[j] = v * gt[j] + sst * (1.f - gt[j]);
    }
    *(float4*)(C + off) = o;
  }
}

// ---------------- reservoir scan: persistent 32-WG kernel, data-as-flag handshake ----------------
// Exchange protocol identical to previous version (self-certifying words, relaxed AGENT-scope
// atomics, parity buffers). Compute path rewritten:
//   * matvec via mfma_f32_16x16x32_bf16: rows on M, 8 batches on N (cols 8..15 padded/discarded).
//     W kept as hi/lo bf16 split (W = W_hi + W_lo) so precision == fp32 W x bf16 h (same as before).
//   * K-reduction inside MFMA: the 64-lane LDS transpose-reduce is gone; only a 2-way K-half
//     combine through a small padded LDS tile remains.
//   * u (xin) prefetched BEFORE the poll loop: its HBM latency hides under the poll.
//   * 32 WGs x 32 rows: halves poll sweep traffic and producer fan-in vs 64 WGs.
// Safety invariants unchanged: a lane stores tag s+1 only after its WG's __syncthreads chain
// (all lanes finished reading tag-s words); a WG reaches tag s+2 (overwriting parity buffer s)
// only after observing all tag-s+1 words.
__global__ __launch_bounds__(256, 1) void reservoir_scan_kernel(
    float* __restrict__ xin_res,       // [8][2048][1024]: in xin, out res states (in-place)
    const float* __restrict__ Wres,    // [1024][1024]
    unsigned* __restrict__ hbuf,       // [2][8192] packed words, zeroed before launch (tag 0, h=0)
    unsigned* __restrict__ unused)
{
  const int tid  = threadIdx.x;
  const int wg   = blockIdx.x;         // 0..31
  const int g    = tid >> 6;           // wave 0..3
  const int lane = tid & 63;
  const int fm   = lane & 15;          // MFMA m (A row) / n (C col)
  const int quad = lane >> 4;          // MFMA k-quad
  const int j0   = wg * 32;            // this WG's 32 hidden rows
  const int rt   = (g & 1) * 16;       // row-tile (0 or 16)
  const int kh   = (g >> 1) * 512;     // K-half (0 or 512)

  __shared__ __align__(16) unsigned short hbf[8 * 1024];   // bf16 h, k-block XOR-swizzled
  __shared__ float red[4 * 16 * 17];                       // [rt2|kh][m][n], n-stride 17 (pad)

  // ---- W fragments in registers: hi/lo bf16 split, MFMA A-layout ----
  // A[m][k_local] with m = fm (row j0+rt+fm), k_local = quad*8 + j within each 32-wide k-frag.
  short8 whi[16], wlo[16];
  {
    const float* wrow = Wres + (size_t)(j0 + rt + fm) * 1024 + kh + quad * 8;
#pragma unroll
    for (int k0 = 0; k0 < 16; ++k0) {
      const float4 wa = *(const float4*)(wrow + k0 * 32);
      const float4 wb = *(const float4*)(wrow + k0 * 32 + 4);
      const float wv[8] = {wa.x, wa.y, wa.z, wa.w, wb.x, wb.y, wb.z, wb.w};
      short8 h8, l8;
#pragma unroll
      for (int j = 0; j < 8; ++j) {
        const unsigned bits = __float_as_uint(wv[j]);
        const unsigned hb   = (bits + 0x8000u) & 0xFFFF0000u;
        const float    lo   = wv[j] - __uint_as_float(hb);
        h8[j] = (short)(hb >> 16);
        l8[j] = (short)((__float_as_uint(lo) + 0x8000u) >> 16);
      }
      whi[k0] = h8; wlo[k0] = l8;
    }
  }

  const int r_out = tid & 31;          // output row within WG
  const int b_out = tid >> 5;          // output batch
  const int jrow  = j0 + r_out;        // global hidden index
  const int bb    = fm & 7;            // B-frag batch (pad lanes 8..15 alias 0..7, cols discarded)
  const unsigned short* hrow = hbf + bb * 1024;

  for (int s = 0; s < S_; ++s) {
    // ---- prefetch u: issued before the poll so HBM latency hides under it ----
    const float u = xin_res[((size_t)b_out * S_ + s) * H_ + jrow];

    // ---- poll+load h^s: staging loads ARE the sync (tag == s certifies payload) ----
    const unsigned tag = (unsigned)s & 0xFFFFu;
    const unsigned* hp = hbuf + (size_t)(s & 1) * 8192;
    unsigned w[32];
    for (;;) {
      bool ok = true;
#pragma unroll
      for (int i = 0; i < 32; ++i)
        w[i] = __hip_atomic_load(hp + tid + 256 * i, __ATOMIC_RELAXED,
                                 __HIP_MEMORY_SCOPE_AGENT);
#pragma unroll
      for (int i = 0; i < 32; ++i) ok &= ((w[i] & 0xFFFFu) == tag);
      if (ok) break;
      __builtin_amdgcn_s_sleep(1);
    }
    __syncthreads();                   // prev-step LDS reads done everywhere; also: all lanes'
                                       // polls complete BEFORE any lane's tag-s+1 store below
    // ---- stage h^s to LDS as bf16, k-block XOR swizzle (conflict-free B-frag ds_read_b128) ----
#pragma unroll
    for (int i = 0; i < 32; ++i) {
      const int p = tid + 256 * i;     // coalesced global sweep position
      const int b = p >> 10, k = p & 1023;
      hbf[b * 1024 + (((k >> 3) ^ b) << 3) + (k & 7)] = (unsigned short)(w[i] >> 16);
    }
    __syncthreads();                   // h^s fully staged

    const float hprev = __uint_as_float(
        (unsigned)hbf[b_out * 1024 + (((jrow >> 3) ^ b_out) << 3) + (jrow & 7)] << 16);

    // ---- MFMA matvec: C[16 rows][16 cols(8 batches used)] over this wave's K-half ----
    floatx4 acc[4];
#pragma unroll
    for (int i = 0; i < 4; ++i) acc[i] = (floatx4){0.f, 0.f, 0.f, 0.f};
#pragma unroll
    for (int k0 = 0; k0 < 16; ++k0) {
      const int K = (kh + k0 * 32 + quad * 8) >> 3;   // 8-aligned k offset, in 8-blocks
      const short8 hb8 = *(const short8*)(hrow + ((K ^ bb) << 3));
      acc[(2 * k0) & 3]     = __builtin_amdgcn_mfma_f32_16x16x32_bf16(whi[k0], hb8, acc[(2 * k0) & 3], 0, 0, 0);
      acc[(2 * k0 + 1) & 3] = __builtin_amdgcn_mfma_f32_16x16x32_bf16(wlo[k0], hb8, acc[(2 * k0 + 1) & 3], 0, 0, 0);
    }
    floatx4 csum;
#pragma unroll
    for (int r = 0; r < 4; ++r) csum[r] = (acc[0][r] + acc[1][r]) + (acc[2][r] + acc[3][r]);

    // ---- 2-way K-half combine via LDS (C layout: col=lane&15, row=quad*4+reg) ----
    {
      const int base = ((g & 1) * 2 + (g >> 1)) * 272;   // [rt-block][kh] tile of 16x17
#pragma unroll
      for (int r = 0; r < 4; ++r)
        red[base + (quad * 4 + r) * 17 + fm] = csum[r];
    }
    __syncthreads();

    const int rb = (r_out >> 4) * 2;
    const float dot = red[rb * 272 + (r_out & 15) * 17 + b_out]
                    + red[(rb + 1) * 272 + (r_out & 15) * 17 + b_out];
    const float hn = tanhf(u + dot);
    const float hv = 0.95f * hn + 0.05f * hprev;

    const unsigned word = ((__float_as_uint(hv) + 0x8000u) & 0xFFFF0000u)
                        | ((unsigned)(s + 1) & 0xFFFFu);
    __hip_atomic_store(hbuf + (size_t)((s + 1) & 1) * 8192 + (size_t)b_out * 1024 + jrow, word,
                       __ATOMIC_RELAXED, __HIP_MEMORY_SCOPE_AGENT);
    xin_res[((size_t)b_out * S_ + s) * H_ + jrow] = hv;   // full fp32 to readout path
    // no drain, no flag, no rendezvous — next iteration's poll is the wait
  }
}

// ---------------- SSM chunked scan ----------------
// within-chunk cumulative delta (tiny)
__global__ __launch_bounds__(128) void cumd_kernel(
    const float* __restrict__ delta, float* __restrict__ cumd)
{
  const int t = threadIdx.x;          // 128 = 8 batches * 16 chunks
  const int b = t >> 4, c = t & 15;
  const int base = b * S_ + c * 128;
  float acc = 0.f;
  for (int i = 0; i < 128; ++i) { acc += delta[base + i]; cumd[base + i] = acc; }
}

// phase A: per-chunk local scan, in-place Bx -> local states; store chunk products
__global__ __launch_bounds__(256) void ssm_partial_kernel(
    const float* __restrict__ delta, const float* __restrict__ Avec,
    float* __restrict__ bx, float* __restrict__ P)
{
  const int idx = blockIdx.x * 256 + threadIdx.x;
  const int h = idx & 1023;
  const int c = (idx >> 10) & 15;
  const int b = idx >> 14;
  const float Ah = Avec[h];
  const float inv = 1.f / (Ah + 1e-8f);
  const float* dp = delta + b * S_ + c * 128;
  float* xp = bx + ((size_t)(b * S_ + c * 128)) * H_ + h;
  float p = 1.f, hl = 0.f;
  for (int t = 0; t < 128; ++t) {
    const float a = __expf(Ah * dp[t]);
    const float bb = xp[(size_t)t * H_] * (1.f - a) * inv;
    hl = a * hl + bb;
    p *= a;
    xp[(size_t)t * H_] = hl;
  }
  P[(b * 16 + c) * 1024 + h] = p;
}

// phase B: sequential combine over 16 chunks -> per-chunk initial states
__global__ __launch_bounds__(256) void ssm_combine_kernel(
    const float* __restrict__ P, const float* __restrict__ local, float* __restrict__ Hin)
{
  const int idx = blockIdx.x * 256 + threadIdx.x;  // 8192
  const int h = idx & 1023;
  const int b = idx >> 10;
  float hh = 0.f;
#pragma unroll
  for (int c = 0; c < 16; ++c) {
    const int o = (b * 16 + c) * 1024 + h;
    Hin[o] = hh;
    hh = P[o] * hh + local[((size_t)(b * S_ + c * 128 + 127)) * H_ + h];
  }
}

// ---------------- host launch ----------------
extern "C" void kernel_launch(void* const* d_in, const int* in_sizes, int n_in,
                              void* d_out, int out_size, void* d_ws, size_t ws_size,
                              hipStream_t stream) {
  (void)in_sizes; (void)n_in; (void)out_size; (void)ws_size;
  const float* x      = (const float*)d_in[0];
  const float* W_in   = (const float*)d_in[1];
  const float* W_res  = (const float*)d_in[2];
  const float* norm_g = (const float*)d_in[3];
  const float* norm_b = (const float*)d_in[4];
  const float* dw     = (const float*)d_in[5];
  const float* db     = (const float*)d_in[6];
  const float* Avec   = (const float*)d_in[7];
  const float* B_w    = (const float*)d_in[8];
  const float* ro_g   = (const float*)d_in[9];
  const float* ro_b   = (const float*)d_in[10];
  const float* ro_w   = (const float*)d_in[11];
  const float* ro_bias= (const float*)d_in[12];
  const float* gate_w = (const float*)d_in[13];
  const float* gate_b = (const float*)d_in[14];
  float* out = (float*)d_out;
  float* ws  = (float*)d_ws;

  float*    buf0   = ws;                    // x_norm, later gate
  float*    buf1   = ws + 16777216;         // xin -> reservoir states (in-place)
  float*    delta  = ws + 33554432;         // [M]
  float*    cumd   = ws + 33570816;         // [M]
  unsigned* hbuf   = (unsigned*)(ws + 33587200);  // [2][8192] packed words
  float2*   stats  = (float2*)(ws + 33603712);
  float*    chP    = ws + 33636480;         // [B,16,1024]
  float*    chH    = ws + 33767552;         // [B,16,1024]

  // 1. layernorm + delta
  ln_delta_kernel<<<M_, 256, 0, stream>>>(x, norm_g, norm_b, dw, db, buf0, delta);
  // 2. xin = x_norm @ W_in^T   -> buf1   (bf16 MFMA)
  gemm_bf16_nt<0><<<1024, 256, 0, stream>>>(buf0, W_in, nullptr, buf1);
  // 3. Bx = x_norm @ B_w^T     -> d_out (scratch)   (bf16 MFMA)
  gemm_bf16_nt<0><<<1024, 256, 0, stream>>>(buf0, B_w, nullptr, out);
  // 4. gate = sigmoid(x @ gate_w^T + gate_b) -> buf0 (x_norm dead)   (bf16 MFMA)
  gemm_bf16_nt<1><<<1024, 256, 0, stream>>>(x, gate_w, gate_b, buf0);
  // 5. ssm chunked scan pieces (independent of reservoir)
  cumd_kernel<<<1, 128, 0, stream>>>(delta, cumd);
  ssm_partial_kernel<<<512, 256, 0, stream>>>(delta, Avec, out, chP);
  ssm_combine_kernel<<<32, 256, 0, stream>>>(chP, out, chH);
  // 6. reservoir scan (zero both parity buffers: word 0 == tag 0 | bf16(0))
  hipMemsetAsync(hbuf, 0, 2 * 8192 * sizeof(unsigned), stream);
  reservoir_scan_kernel<<<32, 256, 0, stream>>>(buf1, W_res, hbuf, nullptr);
  // 7. ro-layernorm stats
  rowstats_kernel<<<M_, 256, 0, stream>>>(buf1, stats);
  // 8. readout GEMM + gelu + ssm reconstruction + gate blend -> d_out
  gemm_readout_kernel<<<2048, 256, 0, stream>>>(buf1, ro_w, ro_bias, stats, ro_g, ro_b,
                                                Avec, cumd, chH, buf0, out);
}